// Round 1
// baseline (187.511 us; speedup 1.0000x reference)
//
#include <hip/hip_runtime.h>
#include <cstdint>

// MillionBucketPyramid: multi-scale hashed embedding lookup with
// sign-bit-conditioned long-range buckets.
// B=32, T=2048, BUCKETS=4e6, E=4, windows {1,2,4,8}, out = (B,T,16) fp32.
//
// Round-3 structure: 1 thread = 1 element (was 4 lanes/elem with duplicated
// gathers + shfl broadcast). Per-wave MLP: 128 unique lines in flight per
// gather round (4x prior). Critical path: hash(k0,k1) -> issue both round-1
// gathers -> hash k2h/k3h under the load latency -> local matvec (no shfl)
// -> round-2 gathers -> stores. fmaf order identical to the validated kernel.

constexpr int TT = 2048;
constexpr int BB = 32;
constexpr uint32_t BUCKETS = 4000000u;
constexpr int EPB = 64;                 // elements (= threads) per block

__device__ constexpr uint64_t PRIMES64[8] = {
    2654435761ull, 2246822519ull, 3266489917ull, 2028178513ull,
    1220703125ull, 1610612741ull,  805306457ull,  402653189ull};

extern "C" __global__ void __launch_bounds__(64)
pyramid_kernel(const int* __restrict__ tokens,
               const float* __restrict__ t0,
               const float* __restrict__ t1,
               const float* __restrict__ t2,
               const float* __restrict__ t3,
               const float* __restrict__ cw,
               float* __restrict__ out)
{
    __shared__ int   stok[EPB + 8];      // 8 halo + 64 tokens
    __shared__ float scw[64];            // cond_w (8x8)

    const int tid = threadIdx.x;
    const int blocksPerRow = TT / EPB;                    // 32
    const int b     = blockIdx.x / blocksPerRow;
    const int tBase = (blockIdx.x % blocksPerRow) * EPB;
    const int* row  = tokens + (size_t)b * TT;

    {
        const int t = tBase - 8 + tid;
        stok[tid] = (t >= 0) ? row[t] : 0;               // pre-sequence pad = 0
        if (tid < 8) stok[64 + tid] = row[tBase + 56 + tid];
    }
    scw[tid] = cw[tid];
    __syncthreads();

    const int el = tid;

    // Cumulative XOR hash; keys for windows 1,2,4,8 are prefixes.
    // stok[el + 7 - j] == tokens[b, t-1-j]
    uint64_t x = (uint64_t)(uint32_t)stok[el + 7] * PRIMES64[0];
    const uint32_t k0 = (uint32_t)(x % BUCKETS);
    x ^= (uint64_t)(uint32_t)stok[el + 6] * PRIMES64[1];
    const uint32_t k1 = (uint32_t)(x % BUCKETS);

    // Round 1: issue both independent gathers as early as possible.
    const float4 v0 = ((const float4* __restrict__)t0)[k0];
    const float4 v1 = ((const float4* __restrict__)t1)[k1];

    // Finish the deeper hashes while round-1 loads are in flight.
    x ^= (uint64_t)(uint32_t)stok[el + 5] * PRIMES64[2];
    x ^= (uint64_t)(uint32_t)stok[el + 4] * PRIMES64[3];
    const uint32_t k2h = (uint32_t)(x % BUCKETS);
    x ^= (uint64_t)(uint32_t)stok[el + 3] * PRIMES64[4];
    x ^= (uint64_t)(uint32_t)stok[el + 2] * PRIMES64[5];
    x ^= (uint64_t)(uint32_t)stok[el + 1] * PRIMES64[6];
    x ^= (uint64_t)(uint32_t)stok[el + 0] * PRIMES64[7];
    const uint32_t k3h = (uint32_t)(x % BUCKETS);

    // Sign-bit matvec, fully in-register (cond_w broadcast from LDS).
    // IDENTICAL fmaf order to the reference-validated kernel.
    const float cat[8] = {v0.x, v0.y, v0.z, v0.w, v1.x, v1.y, v1.z, v1.w};
    uint32_t ck = 0;
#pragma unroll
    for (int o = 0; o < 8; ++o) {
        float acc = 0.f;
#pragma unroll
        for (int d = 0; d < 8; ++d) acc = fmaf(cat[d], scw[o * 8 + d], acc);
        if (acc > 0.f) ck ^= (uint32_t)PRIMES64[o];
    }

    // Round 2: two more independent gathers.
    const uint32_t kk2 = (k2h ^ ck) % BUCKETS;
    const uint32_t kk3 = (k3h ^ ck) % BUCKETS;
    const float4 v2 = ((const float4* __restrict__)t2)[kk2];
    const float4 v3 = ((const float4* __restrict__)t3)[kk3];

    // elemG = blockIdx.x * 64 + tid (grid enumeration collapses exactly).
    float4* __restrict__ o16 =
        (float4*)(out + ((size_t)blockIdx.x * EPB + el) * 16);
    o16[0] = v0;   // short scale 0
    o16[1] = v1;   // short scale 1
    o16[2] = v2;   // long scale 2
    o16[3] = v3;   // long scale 3
}

extern "C" void kernel_launch(void* const* d_in, const int* in_sizes, int n_in,
                              void* d_out, int out_size, void* d_ws, size_t ws_size,
                              hipStream_t stream)
{
    const int*   tokens = (const int*)d_in[0];
    const float* t0     = (const float*)d_in[1];
    const float* t1     = (const float*)d_in[2];
    const float* t2     = (const float*)d_in[3];
    const float* t3     = (const float*)d_in[4];
    const float* cw     = (const float*)d_in[5];
    float*       out    = (float*)d_out;

    const dim3 grid(BB * (TT / EPB));   // 1024 blocks x 64 threads
    pyramid_kernel<<<grid, EPB, 0, stream>>>(tokens, t0, t1, t2, t3, cw, out);
}